// Round 2
// baseline (94.354 us; speedup 1.0000x reference)
//
#include <hip/hip_runtime.h>

#define NQ 4096  // n_qubits (row length); must match reference N

struct c32 { float re, im; };
__device__ __forceinline__ c32 cmul(c32 a, c32 b) {
    return { a.re * b.re - a.im * b.im, a.re * b.im + a.im * b.re };
}

// U = Rz(tz) @ Ry(ty) @ Rx(tx), written as 8 floats:
// [U00.re,U00.im, U01.re,U01.im, U10.re,U10.im, U11.re,U11.im]
__device__ __forceinline__ void compute_U(float tx, float ty, float tz, float* u) {
    float cx, sx, cy, sy, cz, sz;
    sincosf(0.5f * tx, &sx, &cx);
    sincosf(0.5f * ty, &sy, &cy);
    sincosf(0.5f * tz, &sz, &cz);
    // M = Ry @ Rx
    c32 m00 = {  cy * cx,  sy * sx };
    c32 m01 = { -sy * cx, -cy * sx };
    c32 m10 = {  sy * cx, -cy * sx };
    c32 m11 = {  cy * cx, -sy * sx };
    // Rz = diag(ez, conj(ez)), ez = cz - i sz
    c32 ez  = { cz, -sz };
    c32 ezc = { cz,  sz };
    c32 U00 = cmul(ez,  m00), U01 = cmul(ez,  m01);
    c32 U10 = cmul(ezc, m10), U11 = cmul(ezc, m11);
    u[0] = U00.re; u[1] = U00.im; u[2] = U01.re; u[3] = U01.im;
    u[4] = U10.re; u[5] = U10.im; u[6] = U11.re; u[7] = U11.im;
}

__global__ __launch_bounds__(256) void build_U_kernel(
        const float* __restrict__ tx, const float* __restrict__ ty,
        const float* __restrict__ tz, float* __restrict__ Uout, int n_qubits) {
    int n = blockIdx.x * blockDim.x + threadIdx.x;
    if (n >= n_qubits) return;
    float u[8];
    compute_U(tx[n], ty[n], tz[n], u);
    float4* o = reinterpret_cast<float4*>(Uout + n * 8);
    o[0] = make_float4(u[0], u[1], u[2], u[3]);
    o[1] = make_float4(u[4], u[5], u[6], u[7]);
}

// One thread iteration handles 2 consecutive (b,n) pairs. p = b*NQ + n, p even.
// states_re/im: (B, NQ, 2) float32.
// REAL_ONLY: out[p*2 + k] = Re(sum_j s[p][j] * U[n][j][k])   (out_size = B*N*2 floats)
// else:      out[p*4 + 2k + {0,1}] = interleaved complex      (out_size = B*N*4 floats)
template <bool REAL_ONLY, bool USE_TABLE>
__global__ __launch_bounds__(256) void apply_U_kernel(
        const float* __restrict__ sre, const float* __restrict__ sim,
        const float* __restrict__ Utab,
        const float* __restrict__ tx, const float* __restrict__ ty,
        const float* __restrict__ tz,
        float* __restrict__ out, long long n_threads_total) {
    const long long stride = (long long)gridDim.x * blockDim.x;
    for (long long t = (long long)blockIdx.x * blockDim.x + threadIdx.x;
         t < n_threads_total; t += stride) {
        const long long p = t * 2;  // even pair index

        const float4 re = *reinterpret_cast<const float4*>(sre + p * 2);
        const float4 im = *reinterpret_cast<const float4*>(sim + p * 2);

        const int n0 = (int)(p & (NQ - 1));  // even → second pair is n0+1 (no row wrap)

        float ua[8], ub[8];
        if (USE_TABLE) {
            const float4* uq = reinterpret_cast<const float4*>(Utab + n0 * 8);
            float4 q0 = uq[0], q1 = uq[1], q2 = uq[2], q3 = uq[3];
            ua[0]=q0.x; ua[1]=q0.y; ua[2]=q0.z; ua[3]=q0.w;
            ua[4]=q1.x; ua[5]=q1.y; ua[6]=q1.z; ua[7]=q1.w;
            ub[0]=q2.x; ub[1]=q2.y; ub[2]=q2.z; ub[3]=q2.w;
            ub[4]=q3.x; ub[5]=q3.y; ub[6]=q3.z; ub[7]=q3.w;
        } else {
            compute_U(tx[n0],     ty[n0],     tz[n0],     ua);
            compute_U(tx[n0 + 1], ty[n0 + 1], tz[n0 + 1], ub);
        }

        if (REAL_ONLY) {
            // Re(out[k]) = re*U[0][k].re - im*U[0][k].im + re'*U[1][k].re - im'*U[1][k].im
            float4 w;
            w.x = re.x * ua[0] - im.x * ua[1] + re.y * ua[4] - im.y * ua[5];  // pair0 k=0
            w.y = re.x * ua[2] - im.x * ua[3] + re.y * ua[6] - im.y * ua[7];  // pair0 k=1
            w.z = re.z * ub[0] - im.z * ub[1] + re.w * ub[4] - im.w * ub[5];  // pair1 k=0
            w.w = re.z * ub[2] - im.z * ub[3] + re.w * ub[6] - im.w * ub[7];  // pair1 k=1
            *reinterpret_cast<float4*>(out + p * 2) = w;
        } else {
            {
                c32 s0 = { re.x, im.x }, s1 = { re.y, im.y };
                c32 U00 = { ua[0], ua[1] }, U01 = { ua[2], ua[3] };
                c32 U10 = { ua[4], ua[5] }, U11 = { ua[6], ua[7] };
                c32 o0 = cmul(s0, U00), o1 = cmul(s0, U01);
                c32 a0 = cmul(s1, U10), a1 = cmul(s1, U11);
                float4 w = make_float4(o0.re + a0.re, o0.im + a0.im,
                                       o1.re + a1.re, o1.im + a1.im);
                *reinterpret_cast<float4*>(out + p * 4) = w;
            }
            {
                c32 s0 = { re.z, im.z }, s1 = { re.w, im.w };
                c32 U00 = { ub[0], ub[1] }, U01 = { ub[2], ub[3] };
                c32 U10 = { ub[4], ub[5] }, U11 = { ub[6], ub[7] };
                c32 o0 = cmul(s0, U00), o1 = cmul(s0, U01);
                c32 a0 = cmul(s1, U10), a1 = cmul(s1, U11);
                float4 w = make_float4(o0.re + a0.re, o0.im + a0.im,
                                       o1.re + a1.re, o1.im + a1.im);
                *reinterpret_cast<float4*>(out + (p + 1) * 4) = w;
            }
        }
    }
}

extern "C" void kernel_launch(void* const* d_in, const int* in_sizes, int n_in,
                              void* d_out, int out_size, void* d_ws, size_t ws_size,
                              hipStream_t stream) {
    const float* sre = (const float*)d_in[0];
    const float* sim = (const float*)d_in[1];
    const float* tx  = (const float*)d_in[2];
    const float* ty  = (const float*)d_in[3];
    const float* tz  = (const float*)d_in[4];
    float* out = (float*)d_out;

    const int n_qubits = in_sizes[2];                        // N = 4096
    const long long n_floats = (long long)in_sizes[0];       // B*N*2
    const long long n_pairs = n_floats / 2;                  // B*N
    const long long n_threads = n_pairs / 2;                 // 2 pairs per thread
    const int block = 256;
    long long blocks_needed = (n_threads + block - 1) / block;
    const int grid = (int)(blocks_needed < 2048 ? blocks_needed : 2048);

    // Output layout: real-part-only (out_size == B*N*2) vs interleaved complex.
    const bool real_only = ((long long)out_size < 2 * n_floats);

    const size_t u_bytes = (size_t)n_qubits * 8 * sizeof(float);
    const bool use_table = (ws_size >= u_bytes);
    float* Utab = (float*)d_ws;
    if (use_table) {
        build_U_kernel<<<(n_qubits + 255) / 256, 256, 0, stream>>>(tx, ty, tz, Utab, n_qubits);
    }

    if (real_only) {
        if (use_table)
            apply_U_kernel<true, true><<<grid, block, 0, stream>>>(sre, sim, Utab, tx, ty, tz, out, n_threads);
        else
            apply_U_kernel<true, false><<<grid, block, 0, stream>>>(sre, sim, nullptr, tx, ty, tz, out, n_threads);
    } else {
        if (use_table)
            apply_U_kernel<false, true><<<grid, block, 0, stream>>>(sre, sim, Utab, tx, ty, tz, out, n_threads);
        else
            apply_U_kernel<false, false><<<grid, block, 0, stream>>>(sre, sim, nullptr, tx, ty, tz, out, n_threads);
    }
}

// Round 4
// 64.206 us; speedup vs baseline: 1.4696x; 1.4696x over previous
//
#include <hip/hip_runtime.h>

typedef float floatx4 __attribute__((ext_vector_type(4)));

struct c32 { float re, im; };
__device__ __forceinline__ c32 cmul(c32 a, c32 b) {
    return { a.re * b.re - a.im * b.im, a.re * b.im + a.im * b.re };
}

// U = Rz(tz) @ Ry(ty) @ Rx(tx), written as 8 floats:
// [U00.re,U00.im, U01.re,U01.im, U10.re,U10.im, U11.re,U11.im]
__device__ __forceinline__ void compute_U(float tx, float ty, float tz, float* u) {
    float cx, sx, cy, sy, cz, sz;
    sincosf(0.5f * tx, &sx, &cx);
    sincosf(0.5f * ty, &sy, &cy);
    sincosf(0.5f * tz, &sz, &cz);
    // M = Ry @ Rx
    c32 m00 = {  cy * cx,  sy * sx };
    c32 m01 = { -sy * cx, -cy * sx };
    c32 m10 = {  sy * cx, -cy * sx };
    c32 m11 = {  cy * cx, -sy * sx };
    // Rz = diag(ez, conj(ez)), ez = cz - i sz
    c32 ez  = { cz, -sz };
    c32 ezc = { cz,  sz };
    c32 U00 = cmul(ez,  m00), U01 = cmul(ez,  m01);
    c32 U10 = cmul(ezc, m10), U11 = cmul(ezc, m11);
    u[0] = U00.re; u[1] = U00.im; u[2] = U01.re; u[3] = U01.im;
    u[4] = U10.re; u[5] = U10.im; u[6] = U11.re; u[7] = U11.im;
}

// Main kernel: block owns a 512-wide n-slice (256 threads x 2 pairs each),
// iterates over a chunk of the batch dim. U matrices computed ONCE per thread
// into registers; inner loop is pure stream: 2 float4 loads + 1 float4 store.
// Output = real part only: out[(b*N + n)*2 + k] = Re(sum_j s[b,n,j] U[n,j,k]).
__global__ __launch_bounds__(256) void apply_rows_kernel(
        const float* __restrict__ sre, const float* __restrict__ sim,
        const float* __restrict__ tx, const float* __restrict__ ty,
        const float* __restrict__ tz,
        float* __restrict__ out, int N, int B,
        int blocks_per_row, int b_per_chunk) {
    const int row_blk = blockIdx.x % blocks_per_row;
    const int chunk   = blockIdx.x / blocks_per_row;
    const int n0 = row_blk * (blockDim.x * 2) + threadIdx.x * 2;

    float ua[8], ub[8];
    compute_U(tx[n0],     ty[n0],     tz[n0],     ua);
    compute_U(tx[n0 + 1], ty[n0 + 1], tz[n0 + 1], ub);

    const int b_start = chunk * b_per_chunk;
    const int b_end   = (b_start + b_per_chunk < B) ? (b_start + b_per_chunk) : B;

    #pragma unroll 4
    for (int b = b_start; b < b_end; ++b) {
        const long long base = ((long long)b * N + n0) * 2;
        const floatx4 re = *reinterpret_cast<const floatx4*>(sre + base);
        const floatx4 im = *reinterpret_cast<const floatx4*>(sim + base);
        floatx4 w;
        w.x = re.x * ua[0] - im.x * ua[1] + re.y * ua[4] - im.y * ua[5];
        w.y = re.x * ua[2] - im.x * ua[3] + re.y * ua[6] - im.y * ua[7];
        w.z = re.z * ub[0] - im.z * ub[1] + re.w * ub[4] - im.w * ub[5];
        w.w = re.z * ub[2] - im.z * ub[3] + re.w * ub[6] - im.w * ub[7];
        __builtin_nontemporal_store(w, reinterpret_cast<floatx4*>(out + base));
    }
}

// Fallback (general shapes): one thread-iter = 2 consecutive pairs, U recomputed.
__global__ __launch_bounds__(256) void apply_generic_kernel(
        const float* __restrict__ sre, const float* __restrict__ sim,
        const float* __restrict__ tx, const float* __restrict__ ty,
        const float* __restrict__ tz,
        float* __restrict__ out, int N, long long n_threads_total) {
    const long long stride = (long long)gridDim.x * blockDim.x;
    for (long long t = (long long)blockIdx.x * blockDim.x + threadIdx.x;
         t < n_threads_total; t += stride) {
        const long long p = t * 2;
        const floatx4 re = *reinterpret_cast<const floatx4*>(sre + p * 2);
        const floatx4 im = *reinterpret_cast<const floatx4*>(sim + p * 2);
        const int n0 = (int)(p % N);
        float ua[8], ub[8];
        compute_U(tx[n0],     ty[n0],     tz[n0],     ua);
        compute_U(tx[n0 + 1], ty[n0 + 1], tz[n0 + 1], ub);
        floatx4 w;
        w.x = re.x * ua[0] - im.x * ua[1] + re.y * ua[4] - im.y * ua[5];
        w.y = re.x * ua[2] - im.x * ua[3] + re.y * ua[6] - im.y * ua[7];
        w.z = re.z * ub[0] - im.z * ub[1] + re.w * ub[4] - im.w * ub[5];
        w.w = re.z * ub[2] - im.z * ub[3] + re.w * ub[6] - im.w * ub[7];
        *reinterpret_cast<floatx4*>(out + p * 2) = w;
    }
}

extern "C" void kernel_launch(void* const* d_in, const int* in_sizes, int n_in,
                              void* d_out, int out_size, void* d_ws, size_t ws_size,
                              hipStream_t stream) {
    const float* sre = (const float*)d_in[0];
    const float* sim = (const float*)d_in[1];
    const float* tx  = (const float*)d_in[2];
    const float* ty  = (const float*)d_in[3];
    const float* tz  = (const float*)d_in[4];
    float* out = (float*)d_out;

    const int N = in_sizes[2];                          // n_qubits = 4096
    const long long n_floats = (long long)in_sizes[0];  // B*N*2
    const long long n_pairs  = n_floats / 2;            // B*N
    const int B = (int)(n_pairs / N);
    const int block = 256;
    const int pairs_per_block = block * 2;              // 512

    if ((N % pairs_per_block) == 0 && (long long)B * N == n_pairs) {
        const int blocks_per_row = N / pairs_per_block; // 8 at N=4096
        // target ~2048 blocks total
        int b_chunks = 2048 / blocks_per_row;
        if (b_chunks < 1) b_chunks = 1;
        if (b_chunks > B) b_chunks = B;
        const int b_per_chunk = (B + b_chunks - 1) / b_chunks;
        b_chunks = (B + b_per_chunk - 1) / b_per_chunk;
        const int grid = blocks_per_row * b_chunks;
        apply_rows_kernel<<<grid, block, 0, stream>>>(
            sre, sim, tx, ty, tz, out, N, B, blocks_per_row, b_per_chunk);
    } else {
        const long long n_threads = n_pairs / 2;
        long long blocks_needed = (n_threads + block - 1) / block;
        const int grid = (int)(blocks_needed < 2048 ? blocks_needed : 2048);
        apply_generic_kernel<<<grid, block, 0, stream>>>(
            sre, sim, tx, ty, tz, out, N, n_threads);
    }
}